// Round 8
// baseline (493.042 us; speedup 1.0000x reference)
//
#include <hip/hip_runtime.h>
#include <hip/hip_bf16.h>
#include <cstddef>

#define H_   22
#define T_   1000
#define B_   64
#define NSEQ (B_ * H_)      // 1408 sequences (B*C, C==22)
#define KP   22             // conv out channels
#define TP   10             // pooled time positions
#define POOL 100
#define CSTR 488            // hl row stride in fp16 (484 pad-> 488 = 61 uint4)
#define XCH  22             // steps per chunk (x prefetch + hs flush granularity)
#define NCHK ((T_ + XCH - 1) / XCH)   // 46 (last chunk = 10 steps)

typedef _Float16 half2_t __attribute__((ext_vector_type(2)));

__device__ __forceinline__ float sigm(float x) {
    return __fdividef(1.f, 1.f + __expf(-x));     // saturates correctly
}
__device__ __forceinline__ float tanhfast(float x) {
    return 1.f - __fdividef(2.f, __expf(2.f * x) + 1.f);
}

// ---------------------------------------------------------------------------
// Kernel 1: batched independent LSTMs (fp32 in, fp16 hs out).
// 1 wave / block, 2 sequences / wave: lane = (half = lane>>5, hh = lane&31),
// lanes hh>=22 idle (early return). W_hh as 44 packed half2 VGPRs, recurrent
// dot = 44 v_dot2_f32_f16. Weights VGPR-resident (amdgpu_waves_per_eu(1,1)).
//
// Round-8 structural fix: R7 showed issue-count cuts don't move dur ->
// the per-step global_store was the stall: VMEM stores read data/addr VGPRs
// async, so overwriting hf/hout each step forces s_waitcnt vmcnt (~250 cyc
// L2-ack) on the serial chain EVERY step. Now h history for the chunk lives
// in a double-buffered LDS buffer (slots double as the h-exchange), and the
// chunk is flushed with 11 dword stores/lane ONCE per 22 steps. The step
// loop touches global memory zero times.
// x staged via the same-granularity double-buffered LDS ring.
// Single-wave block => DS pipe in-order; wave_barrier() pins ordering.
// hs layout: [b][t][c][h] (contiguous 484-elem dot vector per (b,t)).
// ---------------------------------------------------------------------------
__global__ __launch_bounds__(64)
__attribute__((amdgpu_waves_per_eu(1, 1)))
void lstm_k(
    const float* __restrict__ xin,   // [NSEQ][T_]
    const float* __restrict__ W_ih,  // [88]
    const float* __restrict__ W_hh,  // [88][22]
    const float* __restrict__ b_ih,  // [88]
    const float* __restrict__ b_hh,  // [88]
    _Float16* __restrict__ hsw)      // [B_][T_][22][22]
{
    // [buf][half][slot][unit]; slot stride 24 f16 = 48 B (3x b128 aligned)
    __shared__ __align__(16) _Float16 hist[2][2][XCH][24];
    __shared__ float xb[2][2][XCH + 2];            // [buf][half][step-in-chunk]
    const int lane = threadIdx.x;
    const int half = lane >> 5;
    const int hh   = lane & 31;
    if (hh >= H_) return;
    const int seq = blockIdx.x * 2 + half;
    const int b   = seq / H_;
    const int c   = seq - b * H_;

    // packed fp16 W_hh rows: w2[g][j] = {W[g*22+hh][2j], W[g*22+hh][2j+1]}
    half2_t w2[4][11];
    float wih[4], bias[4];
    #pragma unroll
    for (int g = 0; g < 4; ++g) {
        const int row = g * H_ + hh;
        wih[g]  = W_ih[row];
        bias[g] = b_ih[row] + b_hh[row];
        #pragma unroll
        for (int j = 0; j < 11; ++j) {
            half2_t t;
            t[0] = (_Float16)W_hh[row * H_ + 2 * j];
            t[1] = (_Float16)W_hh[row * H_ + 2 * j + 1];
            w2[g][j] = t;
        }
    }

    // h(-1) = 0 lives in buf1 slot 21 (chunk 0 reads (0+1)&1=1, slot XCH-1)
    hist[1][half][XCH - 1][hh] = (_Float16)0.f;
    float creg = 0.f;
    const float* xp = xin + (size_t)seq * T_;
    xb[0][half][hh] = xp[hh];            // stage chunk 0 (hh < 22 < T_)

    // flush lane mapping: 242 dwords/chunk/half over 22 lanes x 11 iters;
    // idx = i*22+hh -> row = 2i + (hh>=11), col = hh%11 (no division)
    const int r0 = (hh >= 11) ? 1 : 0;
    const int cl = hh - 11 * r0;
    uint* gw = reinterpret_cast<uint*>(hsw);
    const size_t gseq = (size_t)b * T_ * 242 + 11 * c;   // dword index

    for (int chk = 0; chk < NCHK; ++chk) {
        // issue next chunk's coalesced x load now; vmcnt-waited only at the
        // xb publish below (once per chunk)
        const int tn = (chk + 1) * XCH + hh;
        const float xv = (tn < T_) ? xp[tn] : 0.f;

        const int t0  = chk * XCH;
        const int nst = (t0 + XCH <= T_) ? XCH : (T_ - t0);
        const float* xrow = xb[chk & 1][half];
        const _Float16* hrd = &hist[(chk + 1) & 1][half][XCH - 1][0];
        _Float16* hwr = &hist[chk & 1][half][0][0];

        #pragma unroll 2
        for (int s = 0; s < nst; ++s) {
            const float xc = xrow[s];    // ds_read_b32 (broadcast)

            __builtin_amdgcn_wave_barrier();
            uint4 hr[3];
            const uint4* hv = reinterpret_cast<const uint4*>(hrd);
            hr[0] = hv[0]; hr[1] = hv[1]; hr[2] = hv[2];   // 3x ds_read_b128
            __builtin_amdgcn_wave_barrier();
            const half2_t* hp = reinterpret_cast<const half2_t*>(hr);

            float a0 = fmaf(xc, wih[0], bias[0]);
            float a1 = fmaf(xc, wih[1], bias[1]);
            float a2 = fmaf(xc, wih[2], bias[2]);
            float a3 = fmaf(xc, wih[3], bias[3]);
            float b0 = 0.f, b1 = 0.f, b2 = 0.f, b3 = 0.f;
            #pragma unroll
            for (int j = 0; j < 6; ++j) {
                a0 = __builtin_amdgcn_fdot2(hp[j], w2[0][j], a0, false);
                a1 = __builtin_amdgcn_fdot2(hp[j], w2[1][j], a1, false);
                a2 = __builtin_amdgcn_fdot2(hp[j], w2[2][j], a2, false);
                a3 = __builtin_amdgcn_fdot2(hp[j], w2[3][j], a3, false);
            }
            #pragma unroll
            for (int j = 6; j < 11; ++j) {
                b0 = __builtin_amdgcn_fdot2(hp[j], w2[0][j], b0, false);
                b1 = __builtin_amdgcn_fdot2(hp[j], w2[1][j], b1, false);
                b2 = __builtin_amdgcn_fdot2(hp[j], w2[2][j], b2, false);
                b3 = __builtin_amdgcn_fdot2(hp[j], w2[3][j], b3, false);
            }
            a0 += b0; a1 += b1; a2 += b2; a3 += b3;

            const float ig = sigm(a0);
            const float fg = sigm(a1);
            const float gg = tanhfast(a2);
            const float og = sigm(a3);
            creg = fmaf(fg, creg, ig * gg);
            const float hnew = og * tanhfast(creg);
            const _Float16 hf = (_Float16)hnew;
            hwr[hh] = hf;                // ds_write_b16 into history slot s
            __builtin_amdgcn_wave_barrier();
            hrd = hwr;                   // next step reads this slot
            hwr += 24;
        }

        // flush chunk to global: fire-and-forget dword stores; the WAR
        // vmcnt wait (data regs reloaded) happens once per chunk, and the
        // previous chunk's stores are long complete by then.
        {
            const uint* hsrc = reinterpret_cast<const uint*>(&hist[chk & 1][half][0][0]);
            uint* gd = gw + gseq + (size_t)t0 * 242;
            #pragma unroll
            for (int i = 0; i < 11; ++i) {
                const int r = 2 * i + r0;
                if (r < nst)
                    gd[(size_t)r * 242 + cl] = hsrc[r * 12 + cl];
            }
        }

        // publish next chunk's x (waits vmcnt for xv once per chunk)
        xb[(chk + 1) & 1][half][hh] = xv;
    }
}

// ---------------------------------------------------------------------------
// Kernel 2: conv(22ch, kh=22) + bias + ELU + BN(eval) + AvgPool(100).
// One block per (b, pool window p); 256 threads, 220 active: k = tid%22,
// t5 = tid/22 (0..9); each thread: 1 out-channel x 10 rows (t5 + 10i).
// fp16 hs + v_dot2_f32_f16 (__builtin_amdgcn_fdot2): no unpack VALU, 2 MAC
// per op, fp32 accumulate. h-tile LDS reads are wave-broadcast (lanes with
// equal t5 hit the same address). Phased staging 40/40/20 rows.
// ---------------------------------------------------------------------------
__global__ __launch_bounds__(256) void conv_k(
    const _Float16* __restrict__ hsw,        // [B_][T_][22][22]
    const float* __restrict__ conv_w,        // [22][22][22]
    const float* __restrict__ conv_b,        // [22]
    const float* __restrict__ bn_g,
    const float* __restrict__ bn_b,
    const float* __restrict__ bn_m,
    const float* __restrict__ bn_v,
    float* __restrict__ pooled)              // [B_][22][10]
{
    __shared__ __align__(16) _Float16 wl[61 * 22 * 8];  // [cch][k][8]
    __shared__ __align__(16) _Float16 hl[40 * CSTR];
    __shared__ float pp[22 * TP];

    const int tid = threadIdx.x;
    const int b = blockIdx.x / TP;
    const int p = blockIdx.x - b * TP;

    // zero pad elems e=4..7 of chunk 60 (dot positions 484..487)
    if (tid < 22)
        *reinterpret_cast<uint2*>(&wl[(60 * 22 + tid) * 8 + 4]) = make_uint2(0u, 0u);
    // stage conv_w: linear coalesced read; conv_w[k][i][r] -> dot dp=r*22+i,
    // wl[(dp/8)*22 + k][dp%8]
    for (int d = tid; d < 22 * 484; d += 256) {
        const float w = conv_w[d];
        const int k = d / 484, rem = d - k * 484;
        const int i2 = rem / 22, r = rem - i2 * 22;
        const int dp = r * 22 + i2;
        wl[((dp >> 3) * 22 + k) * 8 + (dp & 7)] = (_Float16)w;
    }

    const int k  = tid % 22;          // out channel
    const int t5 = tid / 22;          // row group (0..9 valid)
    const bool act = (tid < 220);

    const float cb = conv_b[k];
    const float mn = bn_m[k];
    const float bt = bn_b[k];
    const float inv = bn_g[k] * __frsqrt_rn(bn_v[k] + 1e-5f);

    float poolsum = 0.f;
    const _Float16* src = hsw + ((size_t)b * T_ + (size_t)p * POOL) * 484;
    const uint4* wl4 = reinterpret_cast<const uint4*>(wl);
    const uint4* hl4 = reinterpret_cast<const uint4*>(hl);

    for (int ph = 0; ph < 3; ++ph) {
        const int rows = (ph == 2) ? 20 : 40;
        const uint2* gsrc = reinterpret_cast<const uint2*>(src + (size_t)(ph * 40) * 484);
        const int n2 = rows * 121;
        for (int idx = tid; idx < n2; idx += 256) {
            const int tr = idx / 121, col = idx - tr * 121;
            reinterpret_cast<uint2*>(&hl[tr * CSTR])[col] = gsrc[idx];
        }
        for (int idx = tid; idx < rows; idx += 256)
            *reinterpret_cast<uint2*>(&hl[idx * CSTR + 484]) = make_uint2(0u, 0u);
        __syncthreads();

        if (act) {
            const int nrt = (ph == 2) ? 2 : 4;     // rows t5 + 10*i
            float acc[4] = {0.f, 0.f, 0.f, 0.f};
            for (int cch = 0; cch < 61; ++cch) {
                const uint4 wv = wl4[cch * 22 + k];
                const half2_t* w2 = reinterpret_cast<const half2_t*>(&wv);
                for (int i = 0; i < nrt; ++i) {
                    const uint4 hv = hl4[(t5 + 10 * i) * 61 + cch];
                    const half2_t* h2 = reinterpret_cast<const half2_t*>(&hv);
                    acc[i] = __builtin_amdgcn_fdot2(h2[0], w2[0], acc[i], false);
                    acc[i] = __builtin_amdgcn_fdot2(h2[1], w2[1], acc[i], false);
                    acc[i] = __builtin_amdgcn_fdot2(h2[2], w2[2], acc[i], false);
                    acc[i] = __builtin_amdgcn_fdot2(h2[3], w2[3], acc[i], false);
                }
            }
            const int nv = (ph == 2) ? 2 : 4;
            for (int i = 0; i < nv; ++i) {
                const float s = acc[i] + cb;
                const float e = (s > 0.f) ? s : (__expf(s) - 1.f);
                poolsum += fmaf(e - mn, inv, bt);
            }
        }
        __syncthreads();
    }

    if (act) pp[k * TP + t5] = poolsum;
    __syncthreads();
    if (tid < 22) {
        float s = 0.f;
        #pragma unroll
        for (int q = 0; q < TP; ++q) s += pp[tid * TP + q];
        pooled[((size_t)b * 22 + tid) * TP + p] = s * 0.01f;
    }
}

// ---------------------------------------------------------------------------
// Kernel 3: FC [64,220] x [220,4]^T + bias -> fp32 out. One thread per output.
// ---------------------------------------------------------------------------
__global__ __launch_bounds__(256) void fc_k(
    const float* __restrict__ pooled,  // [64][220] (idx = k*10+p)
    const float* __restrict__ fc_w,    // [4][220]
    const float* __restrict__ fc_b,    // [4]
    float* __restrict__ out)           // [64][4]
{
    const int tid = threadIdx.x;
    const int b = tid >> 2, n = tid & 3;
    const float* pv = pooled + b * 220;
    const float* wv = fc_w + n * 220;
    float s = fc_b[n];
    #pragma unroll 4
    for (int j = 0; j < 220; ++j)
        s = fmaf(pv[j], wv[j], s);
    out[tid] = s;
}

extern "C" void kernel_launch(void* const* d_in, const int* in_sizes, int n_in,
                              void* d_out, int out_size, void* d_ws, size_t ws_size,
                              hipStream_t stream) {
    const float* xin    = (const float*)d_in[0];
    const float* W_ih   = (const float*)d_in[1];
    const float* W_hh   = (const float*)d_in[2];
    const float* b_ih   = (const float*)d_in[3];
    const float* b_hh   = (const float*)d_in[4];
    const float* conv_w = (const float*)d_in[5];
    const float* conv_b = (const float*)d_in[6];
    const float* bn_g   = (const float*)d_in[7];
    const float* bn_b   = (const float*)d_in[8];
    const float* bn_m   = (const float*)d_in[9];
    const float* bn_v   = (const float*)d_in[10];
    const float* fc_w   = (const float*)d_in[11];
    const float* fc_b   = (const float*)d_in[12];

    _Float16* hsw = (_Float16*)d_ws;                                    // 61,952,000 B
    float* pooled = (float*)((char*)d_ws + (size_t)B_ * T_ * 484 * 2);  // 56,320 B

    lstm_k<<<NSEQ / 2, 64, 0, stream>>>(xin, W_ih, W_hh, b_ih, b_hh, hsw);
    conv_k<<<B_ * TP, 256, 0, stream>>>(hsw, conv_w, conv_b, bn_g, bn_b, bn_m, bn_v, pooled);
    fc_k<<<1, 256, 0, stream>>>(pooled, fc_w, fc_b, (float*)d_out);
}